// Round 2
// baseline (894.906 us; speedup 1.0000x reference)
//
#include <hip/hip_runtime.h>
#include <math.h>

#define NB 32768
#define EPS_REC 1e-4f

// Inter-stage staging (static device globals: graph-capture safe).
__device__ float g_x2[NB * 256];  // stage-1 output: B x 16 x 16
__device__ float g_x3[NB * 16];   // stage-2 output: B x 4 x 4

// HISTORY (do not regress):
//  R5: dual-chain ILP (2 matrices/lane-group) -> occupancy halved, +22% time.
//  R6: __launch_bounds__(128,6) -> 85-reg budget -> HBM scratch spills
//      (FETCH 23->407MB), +60%.
//  R8: 3 sweeps -> absmax 1.375 > 0.69 FAIL. 4 sweeps minimum for two-sided
//      (7->0.125, 5->0.25, 4->0.25, 3->1.375; plateau = fp32 noise floor).
//  R9/R10: two-sided, U in regs: 641us. VALU busy-time ~405us.
//  R11: U moved to LDS: VALU busy-time UNCHANGED (~403us), time +10% from
//       +10 b128 LDS ops/round. Conclusion: kernel is mixed LDS-pipe/VALU
//       bound; b128 chunk staging of A/U/CS *is* the bottleneck, and the
//       AGPR-shuttle theory was wrong.
//  R12 (this): ONE-SIDED (Hestenes) Jacobi. A=PSD => column rotations with
//       Gram-based angles converge A*V = U*Lam; lambda_j = ||a_j||,
//       u_j = a_j/||a_j|| -- NO eigenvector accumulation. Column lives in
//       registers (lane-owned); partner column via DPP (VALU pipe); fixed
//       tournament movement via 20x ds_bpermute_b32 (conflict-free, 256B/op).
//       Hot loop: zero barriers, zero banked LDS. Per round: ~117 VALU + 20
//       bpermute vs ~152 VALU + 17 b128 LDS ops. (64,5)/(64,6) bounds ->
//       ~5-6 waves/SIMD (loop-carried state = col[20] only).
__device__ __forceinline__ void wsync() {
  asm volatile("" ::: "memory");
  __builtin_amdgcn_wave_barrier();
  asm volatile("" ::: "memory");
}

// Swap values between adjacent lanes (lane ^ 1) via DPP quad_perm [1,0,3,2].
// Pairs (2k,2k+1) are even-aligned so they never cross a quad. VALU-pipe op.
__device__ __forceinline__ float dpp_swap1(float x) {
  int xi = __builtin_bit_cast(int, x);
  int yi = __builtin_amdgcn_update_dpp(xi, xi, 0xB1, 0xF, 0xF, true);
  return __builtin_bit_cast(float, yi);
}

// Lane-pull via LDS crossbar (conflict-free permutation). addr = 4*srcLane.
__device__ __forceinline__ float bperm(int addr, float v) {
  int r = __builtin_amdgcn_ds_bpermute(addr, __builtin_bit_cast(int, v));
  return __builtin_bit_cast(float, r);
}

// Tournament (circle-method): content of slot s moves to permf(s); with fixed
// pairing (2k,2k+1), every pair meets exactly once per N-1 rounds.
// srcslot = permf^{-1}: the slot whose content lands in slot `sub`.
__device__ __forceinline__ int srcslot(int sub, int n) {
  return sub == 0 ? 0
       : sub == 1 ? 2
       : sub == n - 2 ? n - 1
       : (sub & 1) ? sub - 2 : sub + 2;
}

// Jacobi rotation (c,s) zeroing the (p,q) off-diagonal of the 2x2 Gram
// [[app,apq],[apq,aqq]]; G = [[c,s],[-s,c]].
__device__ __forceinline__ void rot_cs(float app, float aqq, float apq,
                                       float& c, float& s) {
  float dd = 0.5f * (app - aqq);
  float q2 = apq * apq;
  float hh = dd * dd + q2 + 1e-30f;
  float h = sqrtf(hh);
  float u = fabsf(dd) + h;
  float gi = rsqrtf(u * u + q2);
  c = u * gi;
  float smag = apq * gi;
  s = (dd >= 0.f) ? -smag : smag;
}

// One-sided Jacobi rounds. Lane owns column col[N] in registers. Per round:
//  1) DPP partner swap + in-lane Gram dot d and own norm n (fused loop).
//  2) (c,s) from (n_even, n_odd, d) -- computed identically on both pair
//     lanes (canonical even/odd order), beta = +/- s by parity.
//  3) apply col' = c*col + beta*swp; move to next tournament slot via
//     fixed-address ds_bpermute.
// Zero barriers: single-wave lockstep; bpermute reads VGPRs, no LDS state.
template <int N>
__device__ __forceinline__ void onesided(float* col, int bpAddr, bool isP,
                                         int iters) {
#pragma unroll 1
  for (int it = 0; it < iters; ++it) {
    float swp[N];
    float d0 = 0.f, d1 = 0.f, d2 = 0.f, d3 = 0.f;
    float n0 = 0.f, n1 = 0.f, n2 = 0.f, n3 = 0.f;
#pragma unroll
    for (int i = 0; i < N; i += 4) {
      swp[i] = dpp_swap1(col[i]);
      d0 += col[i] * swp[i];
      n0 += col[i] * col[i];
      swp[i + 1] = dpp_swap1(col[i + 1]);
      d1 += col[i + 1] * swp[i + 1];
      n1 += col[i + 1] * col[i + 1];
      swp[i + 2] = dpp_swap1(col[i + 2]);
      d2 += col[i + 2] * swp[i + 2];
      n2 += col[i + 2] * col[i + 2];
      swp[i + 3] = dpp_swap1(col[i + 3]);
      d3 += col[i + 3] * swp[i + 3];
      n3 += col[i + 3] * col[i + 3];
    }
    float d = (d0 + d1) + (d2 + d3);
    float nOwn = (n0 + n1) + (n2 + n3);
    float nPrt = dpp_swap1(nOwn);
    float ne = isP ? nOwn : nPrt;  // canonical order: both lanes identical
    float no = isP ? nPrt : nOwn;
    float c, s;
    rot_cs(ne, no, d, c, s);
    float beta = isP ? -s : s;
#pragma unroll
    for (int i = 0; i < N; ++i) {
      float v = c * col[i] + beta * swp[i];
      col[i] = bperm(bpAddr, v);
    }
  }
}

// Stage 1: X1 = w1^T X w1 (19 padded to 20), one-sided Jacobi, then
// X2 = Y^T Lamc Y with Y[j] = w2^T u_j. 3 matrices per wave (lanes 60..63
// masked by early return), 64-thread blocks = 1 wave = 3 matrices.
__global__ __launch_bounds__(64, 5) void spd_stage1(
    const float* __restrict__ x, const float* __restrict__ w1,
    const float* __restrict__ w2) {
  __shared__ float4 ZB[3 * 100];  // Z staging, later reused for Y rows
  __shared__ float SL[3 * 20];
  int lane = threadIdx.x;
  int gl = lane / 20;  // 0..3 (3 = idle lanes 60..63)
  int sub = lane - gl * 20;
  int b = blockIdx.x * 3 + gl;
  if (gl >= 3 || b >= NB) return;  // no __syncthreads anywhere: safe
  float4* ZB4 = ZB + gl * 100;
  float* ZBf = (float*)ZB4;
  float* SLg = SL + gl * 20;

  // ---- bilinear: Z = w1^T X (col sub), then X1 col sub = (Z w1) col ----
  const float* xb = x + b * 361;
  float cx[19];
#pragma unroll
  for (int i = 0; i < 19; ++i) cx[i] = (sub < 19) ? xb[i * 19 + sub] : 0.f;
  float z[20];
  z[19] = 0.f;
#pragma unroll
  for (int i = 0; i < 19; ++i) {
    float acc = 0.f;
#pragma unroll
    for (int r = 0; r < 19; ++r) acc += w1[r * 19 + i] * cx[r];
    z[i] = acc;
  }
#pragma unroll
  for (int t = 0; t < 5; ++t)
    ZB4[t * 20 + sub] =
        make_float4(z[4 * t], z[4 * t + 1], z[4 * t + 2], z[4 * t + 3]);
  wsync();
  float wj[19];
#pragma unroll
  for (int r = 0; r < 19; ++r) wj[r] = (sub < 19) ? w1[r * 19 + sub] : 0.f;
  float col[20];
#pragma unroll
  for (int i = 0; i < 20; ++i) col[i] = 0.f;
#pragma unroll
  for (int r = 0; r < 19; ++r) {
    float wr = wj[r];
#pragma unroll
    for (int t = 0; t < 5; ++t) {
      float4 zc = ZB4[t * 20 + r];  // Z rows 4t..4t+3, col r (broadcast)
      col[4 * t + 0] += zc.x * wr;
      col[4 * t + 1] += zc.y * wr;
      col[4 * t + 2] += zc.z * wr;
      col[4 * t + 3] += zc.w * wr;
    }
  }
  // col = X1 column sub; pad column 19 is exactly 0 (stays 0: d=0 => s=0).

  const int bpAddr = (gl * 20 + srcslot(sub, 20)) * 4;
  onesided<20>(col, bpAddr, !(sub & 1), 76);  // 4 sweeps

  // lambda_j = ||col||, u_j = col/||col|| (guarded for the zero pad column)
  float m0 = 0.f, m1 = 0.f, m2 = 0.f, m3 = 0.f;
#pragma unroll
  for (int i = 0; i < 20; i += 4) {
    m0 += col[i] * col[i];
    m1 += col[i + 1] * col[i + 1];
    m2 += col[i + 2] * col[i + 2];
    m3 += col[i + 3] * col[i + 3];
  }
  float nOwn = (m0 + m1) + (m2 + m3);
  float lamc = fmaxf(sqrtf(nOwn), EPS_REC);
  float nrm = nOwn + 1e-30f;
  float inv = rsqrtf(nrm);
  inv = inv * (1.5f - 0.5f * nrm * inv * inv);  // 1 NR step
  // y[k] = sum_{i<19} w2[i][k] * u_j[i]   (in-lane; w2 uniform -> scalar lds)
  float y[16];
#pragma unroll
  for (int k = 0; k < 16; ++k) y[k] = 0.f;
#pragma unroll
  for (int i = 0; i < 19; ++i) {
    float ui = col[i];
#pragma unroll
    for (int k = 0; k < 16; ++k) y[k] += w2[i * 16 + k] * ui;
  }
#pragma unroll
  for (int k = 0; k < 16; ++k) y[k] *= inv;
  wsync();  // Z staging dead; reuse ZB for Y rows
  SLg[sub] = lamc;
#pragma unroll
  for (int t = 0; t < 4; ++t)
    ZB4[sub * 4 + t] =
        make_float4(y[4 * t], y[4 * t + 1], y[4 * t + 2], y[4 * t + 3]);
  wsync();
  // X2[i][sub] = sum_j lamc_j Y[j][i] Y[j][sub]
  if (sub < 16) {
    float acc[16];
#pragma unroll
    for (int i = 0; i < 16; ++i) acc[i] = 0.f;
#pragma unroll
    for (int r = 0; r < 20; ++r) {
      float pr = SLg[r] * ZBf[r * 16 + sub];
#pragma unroll
      for (int t = 0; t < 4; ++t) {
        float4 yr = ZB4[r * 4 + t];  // Y row r, cols 4t..4t+3 (broadcast)
        acc[4 * t + 0] += pr * yr.x;
        acc[4 * t + 1] += pr * yr.y;
        acc[4 * t + 2] += pr * yr.z;
        acc[4 * t + 3] += pr * yr.w;
      }
    }
    float* outb = g_x2 + b * 256;
#pragma unroll
    for (int i = 0; i < 16; ++i) outb[i * 16 + sub] = acc[i];
  }
}

// Stage 2: one-sided Jacobi on 16x16, X3 = Y3^T Lamc Y3 with Y3[j]=w3^T u_j.
// 4 matrices per wave, 64-thread blocks, all lanes active.
__global__ __launch_bounds__(64, 6) void spd_stage2(
    const float* __restrict__ w3) {
  __shared__ float4 Y3L[4 * 16];
  __shared__ float SL2[4 * 16];
  int lane = threadIdx.x;
  int gl = lane >> 4;
  int sub = lane & 15;
  int b = blockIdx.x * 4 + gl;
  float* Y3f = (float*)(Y3L + gl * 16);
  float* SLg = SL2 + gl * 16;

  const float* xb = g_x2 + b * 256;
  float col[16];
#pragma unroll
  for (int i = 0; i < 16; ++i) col[i] = xb[i * 16 + sub];

  const int bpAddr = (gl * 16 + srcslot(sub, 16)) * 4;
  onesided<16>(col, bpAddr, !(sub & 1), 60);  // 4 sweeps

  float m0 = 0.f, m1 = 0.f, m2 = 0.f, m3 = 0.f;
#pragma unroll
  for (int i = 0; i < 16; i += 4) {
    m0 += col[i] * col[i];
    m1 += col[i + 1] * col[i + 1];
    m2 += col[i + 2] * col[i + 2];
    m3 += col[i + 3] * col[i + 3];
  }
  float nOwn = (m0 + m1) + (m2 + m3);
  float lamc = fmaxf(sqrtf(nOwn), EPS_REC);
  float nrm = nOwn + 1e-30f;
  float inv = rsqrtf(nrm);
  inv = inv * (1.5f - 0.5f * nrm * inv * inv);
  float y3[4] = {0.f, 0.f, 0.f, 0.f};
#pragma unroll
  for (int i = 0; i < 16; ++i) {
    float ui = col[i];
#pragma unroll
    for (int j = 0; j < 4; ++j) y3[j] += w3[i * 4 + j] * ui;
  }
#pragma unroll
  for (int j = 0; j < 4; ++j) y3[j] *= inv;
  SLg[sub] = lamc;
  ((float4*)Y3f)[sub] = make_float4(y3[0], y3[1], y3[2], y3[3]);
  wsync();
  int ii = sub >> 2, jj = sub & 3;
  float acc = 0.f;
#pragma unroll
  for (int r = 0; r < 16; ++r)
    acc += SLg[r] * Y3f[r * 4 + ii] * Y3f[r * 4 + jj];
  g_x3[b * 16 + sub] = acc;
}

// Stage 3: per-thread 4x4 LogEig in registers, FC(16->2), log_softmax.
__global__ __launch_bounds__(256) void spd_stage3(const float* __restrict__ fcw,
                                                  float* __restrict__ out) {
  int b = blockIdx.x * 256 + threadIdx.x;
  const float* xb = g_x3 + b * 16;
  float a[4][4];
#pragma unroll
  for (int i = 0; i < 4; ++i)
#pragma unroll
    for (int j = 0; j < 4; ++j) a[i][j] = xb[i * 4 + j];
  float vv[4][4];
#pragma unroll
  for (int i = 0; i < 4; ++i)
#pragma unroll
    for (int j = 0; j < 4; ++j) vv[i][j] = (i == j) ? 1.f : 0.f;

  constexpr int P4[6] = {0, 0, 0, 1, 1, 2};
  constexpr int Q4[6] = {1, 2, 3, 2, 3, 3};
  for (int sw = 0; sw < 6; ++sw) {
#pragma unroll
    for (int e = 0; e < 6; ++e) {
      const int p = P4[e], q = Q4[e];
      float c, s;
      rot_cs(a[p][p], a[q][q], a[p][q], c, s);
#pragma unroll
      for (int j = 0; j < 4; ++j) {
        float xx = a[p][j], yy = a[q][j];
        a[p][j] = c * xx - s * yy;
        a[q][j] = s * xx + c * yy;
      }
#pragma unroll
      for (int i = 0; i < 4; ++i) {
        float xx = a[i][p], yy = a[i][q];
        a[i][p] = c * xx - s * yy;
        a[i][q] = s * xx + c * yy;
      }
#pragma unroll
      for (int i = 0; i < 4; ++i) {
        float xx = vv[i][p], yy = vv[i][q];
        vv[i][p] = c * xx - s * yy;
        vv[i][q] = s * xx + c * yy;
      }
    }
  }
  float ll[4];
#pragma unroll
  for (int r = 0; r < 4; ++r) ll[r] = logf(fmaxf(a[r][r], 1e-12f));
  float feat[16];
#pragma unroll
  for (int i = 0; i < 4; ++i)
#pragma unroll
    for (int j = 0; j < 4; ++j) {
      float acc = 0.f;
#pragma unroll
      for (int r = 0; r < 4; ++r) acc += ll[r] * vv[i][r] * vv[j][r];
      feat[i * 4 + j] = acc;
    }
  float z0 = 0.f, z1 = 0.f;
#pragma unroll
  for (int k = 0; k < 16; ++k) {
    z0 += feat[k] * fcw[2 * k + 0];
    z1 += feat[k] * fcw[2 * k + 1];
  }
  float m = fmaxf(z0, z1);
  float lse = logf(expf(z0 - m) + expf(z1 - m));
  out[b * 2 + 0] = z0 - m - lse;
  out[b * 2 + 1] = z1 - m - lse;
#pragma unroll
  for (int k = 0; k < 16; ++k) out[2 * NB + b * 16 + k] = feat[k];
}

extern "C" void kernel_launch(void* const* d_in, const int* in_sizes, int n_in,
                              void* d_out, int out_size, void* d_ws,
                              size_t ws_size, hipStream_t stream) {
  (void)in_sizes;
  (void)n_in;
  (void)out_size;
  (void)d_ws;
  (void)ws_size;
  const float* x = (const float*)d_in[0];
  const float* w1 = (const float*)d_in[1];
  const float* w2 = (const float*)d_in[2];
  const float* w3 = (const float*)d_in[3];
  const float* fcw = (const float*)d_in[4];
  float* out = (float*)d_out;

  spd_stage1<<<(NB + 2) / 3, 64, 0, stream>>>(x, w1, w2);
  spd_stage2<<<NB / 4, 64, 0, stream>>>(w3);
  spd_stage3<<<NB / 256, 256, 0, stream>>>(fcw, out);
}

// Round 3
// 767.368 us; speedup vs baseline: 1.1662x; 1.1662x over previous
//
#include <hip/hip_runtime.h>
#include <math.h>

#define NB 32768
#define EPS_REC 1e-4f

// Inter-stage staging (static device globals: graph-capture safe).
__device__ float g_x2[NB * 256];  // stage-1 output: B x 16 x 16
__device__ float g_x3[NB * 16];   // stage-2 output: B x 4 x 4

// HISTORY (do not regress):
//  R5: dual-chain ILP (2 matrices/lane-group) -> occupancy halved, +22% time.
//  R6: __launch_bounds__(128,6) -> 85-reg budget -> HBM scratch spills
//      (FETCH 23->407MB), +60%.
//  R8: 3 sweeps -> absmax 1.375 > 0.69 FAIL. 4 sweeps minimum
//      (7->0.125, 5->0.25, 4->0.25, 3->1.375; plateau = fp32 noise floor).
//  R9/R10: two-sided, U in regs: 641us. VALU busy-time ~405us.
//  R11: U moved to LDS: VALU busy-time UNCHANGED, time +10% (b128 LDS ops).
//       Kernel is mixed LDS-pipe/VALU bound; AGPR-shuttle theory wrong.
//  R12: ONE-SIDED (Hestenes) Jacobi, col in regs, DPP partner, bpermute
//       tournament movement. Algorithm PASSED (absmax 0.5) but (64,5)
//       96-reg budget scratch-spilled col[20]+swp[20]: FETCH 492MB,
//       WRITE 961MB (~580B/round), 894us total.
//  R13 (this): same algorithm, spill killed: swp[] array deleted (DPP
//       recomputed in apply loop, +20 cheap VALU/round, -20 registers),
//       launch_bounds (64,4) -> 128-reg budget vs ~40-reg live set.
__device__ __forceinline__ void wsync() {
  asm volatile("" ::: "memory");
  __builtin_amdgcn_wave_barrier();
  asm volatile("" ::: "memory");
}

// Swap values between adjacent lanes (lane ^ 1) via DPP quad_perm [1,0,3,2].
// Pairs (2k,2k+1) are even-aligned so they never cross a quad. VALU-pipe op.
__device__ __forceinline__ float dpp_swap1(float x) {
  int xi = __builtin_bit_cast(int, x);
  int yi = __builtin_amdgcn_update_dpp(xi, xi, 0xB1, 0xF, 0xF, true);
  return __builtin_bit_cast(float, yi);
}

// Lane-pull via LDS crossbar (conflict-free permutation). addr = 4*srcLane.
__device__ __forceinline__ float bperm(int addr, float v) {
  int r = __builtin_amdgcn_ds_bpermute(addr, __builtin_bit_cast(int, v));
  return __builtin_bit_cast(float, r);
}

// Tournament (circle-method): content of slot s moves to permf(s); with fixed
// pairing (2k,2k+1), every pair meets exactly once per N-1 rounds.
// srcslot = permf^{-1}: the slot whose content lands in slot `sub`.
__device__ __forceinline__ int srcslot(int sub, int n) {
  return sub == 0 ? 0
       : sub == 1 ? 2
       : sub == n - 2 ? n - 1
       : (sub & 1) ? sub - 2 : sub + 2;
}

// Jacobi rotation (c,s) zeroing the (p,q) off-diagonal of the 2x2 Gram
// [[app,apq],[apq,aqq]]; G = [[c,s],[-s,c]].
__device__ __forceinline__ void rot_cs(float app, float aqq, float apq,
                                       float& c, float& s) {
  float dd = 0.5f * (app - aqq);
  float q2 = apq * apq;
  float hh = dd * dd + q2 + 1e-30f;
  float h = sqrtf(hh);
  float u = fabsf(dd) + h;
  float gi = rsqrtf(u * u + q2);
  c = u * gi;
  float smag = apq * gi;
  s = (dd >= 0.f) ? -smag : smag;
}

// One-sided Jacobi rounds. Lane owns column col[N] in registers. Per round:
//  1) DPP partner swap + in-lane Gram dot d and own norm n (fused loop).
//  2) (c,s) from (n_even, n_odd, d) -- computed identically on both pair
//     lanes (canonical even/odd order), beta = +/- s by parity.
//  3) apply col' = c*col + beta*dpp(col) (DPP recomputed: partner values are
//     still pre-update at that point in the instruction stream), then move
//     to next tournament slot via fixed-address ds_bpermute.
// Zero barriers: single-wave lockstep; bpermute reads VGPRs, no LDS state.
// Loop-carried register state: col[N] ONLY (spill-proof by design).
template <int N>
__device__ __forceinline__ void onesided(float* col, int bpAddr, bool isP,
                                         int iters) {
#pragma unroll 1
  for (int it = 0; it < iters; ++it) {
    float d0 = 0.f, d1 = 0.f, d2 = 0.f, d3 = 0.f;
    float n0 = 0.f, n1 = 0.f, n2 = 0.f, n3 = 0.f;
#pragma unroll
    for (int i = 0; i < N; i += 4) {
      float s0 = dpp_swap1(col[i]);
      d0 += col[i] * s0;
      n0 += col[i] * col[i];
      float s1 = dpp_swap1(col[i + 1]);
      d1 += col[i + 1] * s1;
      n1 += col[i + 1] * col[i + 1];
      float s2 = dpp_swap1(col[i + 2]);
      d2 += col[i + 2] * s2;
      n2 += col[i + 2] * col[i + 2];
      float s3 = dpp_swap1(col[i + 3]);
      d3 += col[i + 3] * s3;
      n3 += col[i + 3] * col[i + 3];
    }
    float d = (d0 + d1) + (d2 + d3);
    float nOwn = (n0 + n1) + (n2 + n3);
    float nPrt = dpp_swap1(nOwn);
    float ne = isP ? nOwn : nPrt;  // canonical order: both lanes identical
    float no = isP ? nPrt : nOwn;
    float c, s;
    rot_cs(ne, no, d, c, s);
    float beta = isP ? -s : s;
#pragma unroll
    for (int i = 0; i < N; ++i) {
      float v = c * col[i] + beta * dpp_swap1(col[i]);
      col[i] = bperm(bpAddr, v);
    }
  }
}

// Stage 1: X1 = w1^T X w1 (19 padded to 20), one-sided Jacobi, then
// X2 = Y^T Lamc Y with Y[j] = w2^T u_j. 3 matrices per wave (lanes 60..63
// masked by early return), 64-thread blocks = 1 wave = 3 matrices.
__global__ __launch_bounds__(64, 4) void spd_stage1(
    const float* __restrict__ x, const float* __restrict__ w1,
    const float* __restrict__ w2) {
  __shared__ float4 ZB[3 * 100];  // Z staging, later reused for Y rows
  __shared__ float SL[3 * 20];
  int lane = threadIdx.x;
  int gl = lane / 20;  // 0..3 (3 = idle lanes 60..63)
  int sub = lane - gl * 20;
  int b = blockIdx.x * 3 + gl;
  if (gl >= 3 || b >= NB) return;  // no __syncthreads anywhere: safe
  float4* ZB4 = ZB + gl * 100;
  float* ZBf = (float*)ZB4;
  float* SLg = SL + gl * 20;

  // ---- bilinear: Z = w1^T X (col sub), then X1 col sub = (Z w1) col ----
  const float* xb = x + b * 361;
  float cx[19];
#pragma unroll
  for (int i = 0; i < 19; ++i) cx[i] = (sub < 19) ? xb[i * 19 + sub] : 0.f;
  float z[20];
  z[19] = 0.f;
#pragma unroll
  for (int i = 0; i < 19; ++i) {
    float acc = 0.f;
#pragma unroll
    for (int r = 0; r < 19; ++r) acc += w1[r * 19 + i] * cx[r];
    z[i] = acc;
  }
#pragma unroll
  for (int t = 0; t < 5; ++t)
    ZB4[t * 20 + sub] =
        make_float4(z[4 * t], z[4 * t + 1], z[4 * t + 2], z[4 * t + 3]);
  wsync();
  float wj[19];
#pragma unroll
  for (int r = 0; r < 19; ++r) wj[r] = (sub < 19) ? w1[r * 19 + sub] : 0.f;
  float col[20];
#pragma unroll
  for (int i = 0; i < 20; ++i) col[i] = 0.f;
#pragma unroll
  for (int r = 0; r < 19; ++r) {
    float wr = wj[r];
#pragma unroll
    for (int t = 0; t < 5; ++t) {
      float4 zc = ZB4[t * 20 + r];  // Z rows 4t..4t+3, col r (broadcast)
      col[4 * t + 0] += zc.x * wr;
      col[4 * t + 1] += zc.y * wr;
      col[4 * t + 2] += zc.z * wr;
      col[4 * t + 3] += zc.w * wr;
    }
  }
  // col = X1 column sub; pad column 19 is exactly 0 (stays 0: d=0 => s=0).

  const int bpAddr = (gl * 20 + srcslot(sub, 20)) * 4;
  onesided<20>(col, bpAddr, !(sub & 1), 76);  // 4 sweeps

  // lambda_j = ||col||, u_j = col/||col|| (guarded for the zero pad column)
  float m0 = 0.f, m1 = 0.f, m2 = 0.f, m3 = 0.f;
#pragma unroll
  for (int i = 0; i < 20; i += 4) {
    m0 += col[i] * col[i];
    m1 += col[i + 1] * col[i + 1];
    m2 += col[i + 2] * col[i + 2];
    m3 += col[i + 3] * col[i + 3];
  }
  float nOwn = (m0 + m1) + (m2 + m3);
  float lamc = fmaxf(sqrtf(nOwn), EPS_REC);
  float nrm = nOwn + 1e-30f;
  float inv = rsqrtf(nrm);
  inv = inv * (1.5f - 0.5f * nrm * inv * inv);  // 1 NR step
  // y[k] = sum_{i<19} w2[i][k] * u_j[i]   (in-lane; w2 uniform -> scalar lds)
  float y[16];
#pragma unroll
  for (int k = 0; k < 16; ++k) y[k] = 0.f;
#pragma unroll
  for (int i = 0; i < 19; ++i) {
    float ui = col[i];
#pragma unroll
    for (int k = 0; k < 16; ++k) y[k] += w2[i * 16 + k] * ui;
  }
#pragma unroll
  for (int k = 0; k < 16; ++k) y[k] *= inv;
  wsync();  // Z staging dead; reuse ZB for Y rows
  SLg[sub] = lamc;
#pragma unroll
  for (int t = 0; t < 4; ++t)
    ZB4[sub * 4 + t] =
        make_float4(y[4 * t], y[4 * t + 1], y[4 * t + 2], y[4 * t + 3]);
  wsync();
  // X2[i][sub] = sum_j lamc_j Y[j][i] Y[j][sub]
  if (sub < 16) {
    float acc[16];
#pragma unroll
    for (int i = 0; i < 16; ++i) acc[i] = 0.f;
#pragma unroll
    for (int r = 0; r < 20; ++r) {
      float pr = SLg[r] * ZBf[r * 16 + sub];
#pragma unroll
      for (int t = 0; t < 4; ++t) {
        float4 yr = ZB4[r * 4 + t];  // Y row r, cols 4t..4t+3 (broadcast)
        acc[4 * t + 0] += pr * yr.x;
        acc[4 * t + 1] += pr * yr.y;
        acc[4 * t + 2] += pr * yr.z;
        acc[4 * t + 3] += pr * yr.w;
      }
    }
    float* outb = g_x2 + b * 256;
#pragma unroll
    for (int i = 0; i < 16; ++i) outb[i * 16 + sub] = acc[i];
  }
}

// Stage 2: one-sided Jacobi on 16x16, X3 = Y3^T Lamc Y3 with Y3[j]=w3^T u_j.
// 4 matrices per wave, 64-thread blocks, all lanes active.
__global__ __launch_bounds__(64, 4) void spd_stage2(
    const float* __restrict__ w3) {
  __shared__ float4 Y3L[4 * 16];
  __shared__ float SL2[4 * 16];
  int lane = threadIdx.x;
  int gl = lane >> 4;
  int sub = lane & 15;
  int b = blockIdx.x * 4 + gl;
  float* Y3f = (float*)(Y3L + gl * 16);
  float* SLg = SL2 + gl * 16;

  const float* xb = g_x2 + b * 256;
  float col[16];
#pragma unroll
  for (int i = 0; i < 16; ++i) col[i] = xb[i * 16 + sub];

  const int bpAddr = (gl * 16 + srcslot(sub, 16)) * 4;
  onesided<16>(col, bpAddr, !(sub & 1), 60);  // 4 sweeps

  float m0 = 0.f, m1 = 0.f, m2 = 0.f, m3 = 0.f;
#pragma unroll
  for (int i = 0; i < 16; i += 4) {
    m0 += col[i] * col[i];
    m1 += col[i + 1] * col[i + 1];
    m2 += col[i + 2] * col[i + 2];
    m3 += col[i + 3] * col[i + 3];
  }
  float nOwn = (m0 + m1) + (m2 + m3);
  float lamc = fmaxf(sqrtf(nOwn), EPS_REC);
  float nrm = nOwn + 1e-30f;
  float inv = rsqrtf(nrm);
  inv = inv * (1.5f - 0.5f * nrm * inv * inv);
  float y3[4] = {0.f, 0.f, 0.f, 0.f};
#pragma unroll
  for (int i = 0; i < 16; ++i) {
    float ui = col[i];
#pragma unroll
    for (int j = 0; j < 4; ++j) y3[j] += w3[i * 4 + j] * ui;
  }
#pragma unroll
  for (int j = 0; j < 4; ++j) y3[j] *= inv;
  SLg[sub] = lamc;
  ((float4*)Y3f)[sub] = make_float4(y3[0], y3[1], y3[2], y3[3]);
  wsync();
  int ii = sub >> 2, jj = sub & 3;
  float acc = 0.f;
#pragma unroll
  for (int r = 0; r < 16; ++r)
    acc += SLg[r] * Y3f[r * 4 + ii] * Y3f[r * 4 + jj];
  g_x3[b * 16 + sub] = acc;
}

// Stage 3: per-thread 4x4 LogEig in registers, FC(16->2), log_softmax.
__global__ __launch_bounds__(256) void spd_stage3(const float* __restrict__ fcw,
                                                  float* __restrict__ out) {
  int b = blockIdx.x * 256 + threadIdx.x;
  const float* xb = g_x3 + b * 16;
  float a[4][4];
#pragma unroll
  for (int i = 0; i < 4; ++i)
#pragma unroll
    for (int j = 0; j < 4; ++j) a[i][j] = xb[i * 4 + j];
  float vv[4][4];
#pragma unroll
  for (int i = 0; i < 4; ++i)
#pragma unroll
    for (int j = 0; j < 4; ++j) vv[i][j] = (i == j) ? 1.f : 0.f;

  constexpr int P4[6] = {0, 0, 0, 1, 1, 2};
  constexpr int Q4[6] = {1, 2, 3, 2, 3, 3};
  for (int sw = 0; sw < 6; ++sw) {
#pragma unroll
    for (int e = 0; e < 6; ++e) {
      const int p = P4[e], q = Q4[e];
      float c, s;
      rot_cs(a[p][p], a[q][q], a[p][q], c, s);
#pragma unroll
      for (int j = 0; j < 4; ++j) {
        float xx = a[p][j], yy = a[q][j];
        a[p][j] = c * xx - s * yy;
        a[q][j] = s * xx + c * yy;
      }
#pragma unroll
      for (int i = 0; i < 4; ++i) {
        float xx = a[i][p], yy = a[i][q];
        a[i][p] = c * xx - s * yy;
        a[i][q] = s * xx + c * yy;
      }
#pragma unroll
      for (int i = 0; i < 4; ++i) {
        float xx = vv[i][p], yy = vv[i][q];
        vv[i][p] = c * xx - s * yy;
        vv[i][q] = s * xx + c * yy;
      }
    }
  }
  float ll[4];
#pragma unroll
  for (int r = 0; r < 4; ++r) ll[r] = logf(fmaxf(a[r][r], 1e-12f));
  float feat[16];
#pragma unroll
  for (int i = 0; i < 4; ++i)
#pragma unroll
    for (int j = 0; j < 4; ++j) {
      float acc = 0.f;
#pragma unroll
      for (int r = 0; r < 4; ++r) acc += ll[r] * vv[i][r] * vv[j][r];
      feat[i * 4 + j] = acc;
    }
  float z0 = 0.f, z1 = 0.f;
#pragma unroll
  for (int k = 0; k < 16; ++k) {
    z0 += feat[k] * fcw[2 * k + 0];
    z1 += feat[k] * fcw[2 * k + 1];
  }
  float m = fmaxf(z0, z1);
  float lse = logf(expf(z0 - m) + expf(z1 - m));
  out[b * 2 + 0] = z0 - m - lse;
  out[b * 2 + 1] = z1 - m - lse;
#pragma unroll
  for (int k = 0; k < 16; ++k) out[2 * NB + b * 16 + k] = feat[k];
}

extern "C" void kernel_launch(void* const* d_in, const int* in_sizes, int n_in,
                              void* d_out, int out_size, void* d_ws,
                              size_t ws_size, hipStream_t stream) {
  (void)in_sizes;
  (void)n_in;
  (void)out_size;
  (void)d_ws;
  (void)ws_size;
  const float* x = (const float*)d_in[0];
  const float* w1 = (const float*)d_in[1];
  const float* w2 = (const float*)d_in[2];
  const float* w3 = (const float*)d_in[3];
  const float* fcw = (const float*)d_in[4];
  float* out = (float*)d_out;

  spd_stage1<<<(NB + 2) / 3, 64, 0, stream>>>(x, w1, w2);
  spd_stage2<<<NB / 4, 64, 0, stream>>>(w3);
  spd_stage3<<<NB / 256, 256, 0, stream>>>(fcw, out);
}

// Round 4
// 652.333 us; speedup vs baseline: 1.3719x; 1.1763x over previous
//
#include <hip/hip_runtime.h>
#include <math.h>

#define NB 32768
#define EPS_REC 1e-4f

// Inter-stage staging (static device globals: graph-capture safe).
__device__ float g_x2[NB * 256];  // stage-1 output: B x 16 x 16
__device__ float g_x3[NB * 16];   // stage-2 output: B x 4 x 4

// HISTORY (do not regress):
//  R5: dual-chain ILP (2 matrices/lane-group) -> occupancy halved, +22% time.
//  R6: __launch_bounds__(128,6) -> 85-reg budget -> HBM scratch spills
//      (FETCH 23->407MB), +60%.
//  R8: 3 sweeps -> absmax 1.375 > 0.69 FAIL. 4 sweeps minimum
//      (7->0.125, 5->0.25, 4->0.25, 3->1.375; plateau = fp32 noise floor).
//  R9/R10: two-sided, U in regs: 641us. VALU busy-time ~405us.
//  R11: U moved to LDS: VALU busy-time UNCHANGED, time +10% (b128 LDS ops).
//       Kernel is mixed LDS-pipe/VALU bound. Preamble/tail arrays (cx/z/wj/
//       y/acc, static-index, short-lived) were register-clean: FETCH 23MB.
//  R12: ONE-SIDED (Hestenes) Jacobi in "registers": PASSED (absmax 0.5) but
//       FETCH 492MB/WRITE 961MB scratch traffic, 894us.
//  R13: swp[] deleted, (64,4): still FETCH 441/WRITE 868, VGPR=64 (HALF the
//       budget) -> NOT register pressure. Diagnosis: col[] alloca never
//       SROA'd (array decays to float* through onesided(), loop-carried
//       through pragma-unroll-1 + ds_bpermute round-trip) -> every round
//       hits scratch; L1/L2 absorb some, 1.3GB leaks to HBM.
//  R14 (this): Jacobi state = NAMED float4 vars (a0..a4 / b0..b3), round
//       function takes float4& refs, fully unrolled, zero arrays in the hot
//       loop. Preamble/tail keep short-lived static arrays (R11-proven).
__device__ __forceinline__ void wsync() {
  asm volatile("" ::: "memory");
  __builtin_amdgcn_wave_barrier();
  asm volatile("" ::: "memory");
}

// Swap values between adjacent lanes (lane ^ 1) via DPP quad_perm [1,0,3,2].
// Pairs (2k,2k+1) are even-aligned so they never cross a quad. VALU-pipe op.
__device__ __forceinline__ float dpp_swap1(float x) {
  int xi = __builtin_bit_cast(int, x);
  int yi = __builtin_amdgcn_update_dpp(xi, xi, 0xB1, 0xF, 0xF, true);
  return __builtin_bit_cast(float, yi);
}

// Lane-pull via LDS crossbar (conflict-free permutation). addr = 4*srcLane.
__device__ __forceinline__ float bperm(int addr, float v) {
  int r = __builtin_amdgcn_ds_bpermute(addr, __builtin_bit_cast(int, v));
  return __builtin_bit_cast(float, r);
}

// Tournament (circle-method): content of slot s moves to permf(s); with fixed
// pairing (2k,2k+1), every pair meets exactly once per N-1 rounds.
// srcslot = permf^{-1}: the slot whose content lands in slot `sub`.
__device__ __forceinline__ int srcslot(int sub, int n) {
  return sub == 0 ? 0
       : sub == 1 ? 2
       : sub == n - 2 ? n - 1
       : (sub & 1) ? sub - 2 : sub + 2;
}

// Jacobi rotation (c,s) zeroing the (p,q) off-diagonal of the 2x2 Gram
// [[app,apq],[apq,aqq]]; G = [[c,s],[-s,c]].
__device__ __forceinline__ void rot_cs(float app, float aqq, float apq,
                                       float& c, float& s) {
  float dd = 0.5f * (app - aqq);
  float q2 = apq * apq;
  float hh = dd * dd + q2 + 1e-30f;
  float h = sqrtf(hh);
  float u = fabsf(dd) + h;
  float gi = rsqrtf(u * u + q2);
  c = u * gi;
  float smag = apq * gi;
  s = (dd >= 0.f) ? -smag : smag;
}

// Gram partial: d += <own, partner>, n += <own, own> for 4 components.
__device__ __forceinline__ void gram4(float4 a, float& d0, float& d1,
                                      float& d2, float& d3, float& n0,
                                      float& n1, float& n2, float& n3) {
  float s0 = dpp_swap1(a.x);
  d0 += a.x * s0;
  n0 += a.x * a.x;
  float s1 = dpp_swap1(a.y);
  d1 += a.y * s1;
  n1 += a.y * a.y;
  float s2 = dpp_swap1(a.z);
  d2 += a.z * s2;
  n2 += a.z * a.z;
  float s3 = dpp_swap1(a.w);
  d3 += a.w * s3;
  n3 += a.w * a.w;
}

// Apply rotation + tournament move for 4 components. DPP reads pre-update
// partner values (both pair lanes are at the same program point, and the
// result goes to a fresh value, not back into a before all reads complete).
__device__ __forceinline__ float4 appmv4(float4 a, float c, float beta,
                                         int bpAddr) {
  float4 r;
  r.x = bperm(bpAddr, fmaf(beta, dpp_swap1(a.x), c * a.x));
  r.y = bperm(bpAddr, fmaf(beta, dpp_swap1(a.y), c * a.y));
  r.z = bperm(bpAddr, fmaf(beta, dpp_swap1(a.z), c * a.z));
  r.w = bperm(bpAddr, fmaf(beta, dpp_swap1(a.w), c * a.w));
  return r;
}

// One one-sided Jacobi round on a 20-row column held in a0..a4.
__device__ __forceinline__ void round20(float4& a0, float4& a1, float4& a2,
                                        float4& a3, float4& a4, int bpAddr,
                                        bool isP) {
  float d0 = 0.f, d1 = 0.f, d2 = 0.f, d3 = 0.f;
  float n0 = 0.f, n1 = 0.f, n2 = 0.f, n3 = 0.f;
  gram4(a0, d0, d1, d2, d3, n0, n1, n2, n3);
  gram4(a1, d0, d1, d2, d3, n0, n1, n2, n3);
  gram4(a2, d0, d1, d2, d3, n0, n1, n2, n3);
  gram4(a3, d0, d1, d2, d3, n0, n1, n2, n3);
  gram4(a4, d0, d1, d2, d3, n0, n1, n2, n3);
  float d = (d0 + d1) + (d2 + d3);
  float nOwn = (n0 + n1) + (n2 + n3);
  float nPrt = dpp_swap1(nOwn);
  float ne = isP ? nOwn : nPrt;  // canonical order: both pair lanes identical
  float no = isP ? nPrt : nOwn;
  float c, s;
  rot_cs(ne, no, d, c, s);
  float beta = isP ? -s : s;
  a0 = appmv4(a0, c, beta, bpAddr);
  a1 = appmv4(a1, c, beta, bpAddr);
  a2 = appmv4(a2, c, beta, bpAddr);
  a3 = appmv4(a3, c, beta, bpAddr);
  a4 = appmv4(a4, c, beta, bpAddr);
}

// One one-sided Jacobi round on a 16-row column held in b0..b3.
__device__ __forceinline__ void round16(float4& b0, float4& b1, float4& b2,
                                        float4& b3, int bpAddr, bool isP) {
  float d0 = 0.f, d1 = 0.f, d2 = 0.f, d3 = 0.f;
  float n0 = 0.f, n1 = 0.f, n2 = 0.f, n3 = 0.f;
  gram4(b0, d0, d1, d2, d3, n0, n1, n2, n3);
  gram4(b1, d0, d1, d2, d3, n0, n1, n2, n3);
  gram4(b2, d0, d1, d2, d3, n0, n1, n2, n3);
  gram4(b3, d0, d1, d2, d3, n0, n1, n2, n3);
  float d = (d0 + d1) + (d2 + d3);
  float nOwn = (n0 + n1) + (n2 + n3);
  float nPrt = dpp_swap1(nOwn);
  float ne = isP ? nOwn : nPrt;
  float no = isP ? nPrt : nOwn;
  float c, s;
  rot_cs(ne, no, d, c, s);
  float beta = isP ? -s : s;
  b0 = appmv4(b0, c, beta, bpAddr);
  b1 = appmv4(b1, c, beta, bpAddr);
  b2 = appmv4(b2, c, beta, bpAddr);
  b3 = appmv4(b3, c, beta, bpAddr);
}

__device__ __forceinline__ float sq4(float4 a) {
  return (a.x * a.x + a.y * a.y) + (a.z * a.z + a.w * a.w);
}

// Stage 1: X1 = w1^T X w1 (19 padded to 20), one-sided Jacobi, then
// X2 = Y^T Lamc Y with Y[j] = w2^T u_j. 3 matrices per wave (lanes 60..63
// masked by early return), 64-thread blocks = 1 wave = 3 matrices.
__global__ __launch_bounds__(64, 4) void spd_stage1(
    const float* __restrict__ x, const float* __restrict__ w1,
    const float* __restrict__ w2) {
  __shared__ float4 ZB[3 * 100];  // Z staging, later reused for Y rows
  __shared__ float SL[3 * 20];
  int lane = threadIdx.x;
  int gl = lane / 20;  // 0..3 (3 = idle lanes 60..63)
  int sub = lane - gl * 20;
  int b = blockIdx.x * 3 + gl;
  if (gl >= 3 || b >= NB) return;  // no __syncthreads anywhere: safe
  float4* ZB4 = ZB + gl * 100;
  float* ZBf = (float*)ZB4;
  float* SLg = SL + gl * 20;

  // ---- bilinear: Z = w1^T X (col sub), then X1 col sub = (Z w1) col ----
  const float* xb = x + b * 361;
  float cx[19];
#pragma unroll
  for (int i = 0; i < 19; ++i) cx[i] = (sub < 19) ? xb[i * 19 + sub] : 0.f;
  float z[20];
  z[19] = 0.f;
#pragma unroll
  for (int i = 0; i < 19; ++i) {
    float acc = 0.f;
#pragma unroll
    for (int r = 0; r < 19; ++r) acc += w1[r * 19 + i] * cx[r];
    z[i] = acc;
  }
#pragma unroll
  for (int t = 0; t < 5; ++t)
    ZB4[t * 20 + sub] =
        make_float4(z[4 * t], z[4 * t + 1], z[4 * t + 2], z[4 * t + 3]);
  wsync();
  float wj[19];
#pragma unroll
  for (int r = 0; r < 19; ++r) wj[r] = (sub < 19) ? w1[r * 19 + sub] : 0.f;
  float4 a0 = make_float4(0.f, 0.f, 0.f, 0.f);
  float4 a1 = a0, a2 = a0, a3 = a0, a4 = a0;
#pragma unroll
  for (int r = 0; r < 19; ++r) {
    float wr = wj[r];
    float4 zc;
    zc = ZB4[0 * 20 + r];
    a0.x += zc.x * wr; a0.y += zc.y * wr; a0.z += zc.z * wr; a0.w += zc.w * wr;
    zc = ZB4[1 * 20 + r];
    a1.x += zc.x * wr; a1.y += zc.y * wr; a1.z += zc.z * wr; a1.w += zc.w * wr;
    zc = ZB4[2 * 20 + r];
    a2.x += zc.x * wr; a2.y += zc.y * wr; a2.z += zc.z * wr; a2.w += zc.w * wr;
    zc = ZB4[3 * 20 + r];
    a3.x += zc.x * wr; a3.y += zc.y * wr; a3.z += zc.z * wr; a3.w += zc.w * wr;
    zc = ZB4[4 * 20 + r];
    a4.x += zc.x * wr; a4.y += zc.y * wr; a4.z += zc.z * wr; a4.w += zc.w * wr;
  }
  // a0..a4 = X1 column sub; pad column 19 is exactly 0 (stays 0: d=0 => s=0).

  const int bpAddr = (gl * 20 + srcslot(sub, 20)) * 4;
  const bool isP = !(sub & 1);
#pragma unroll 1
  for (int it = 0; it < 76; ++it)  // 4 sweeps (validated minimum)
    round20(a0, a1, a2, a3, a4, bpAddr, isP);

  // lambda_j = ||col||, u_j = col/||col|| (guarded for the zero pad column)
  float nOwn = ((sq4(a0) + sq4(a1)) + (sq4(a2) + sq4(a3))) + sq4(a4);
  float lamc = fmaxf(sqrtf(nOwn), EPS_REC);
  float nrm = nOwn + 1e-30f;
  float inv = rsqrtf(nrm);
  inv = inv * (1.5f - 0.5f * nrm * inv * inv);  // 1 NR step
  // Unpack to a short-lived static array (R11-proven clean) for the tail.
  float cv[20];
  cv[0] = a0.x; cv[1] = a0.y; cv[2] = a0.z; cv[3] = a0.w;
  cv[4] = a1.x; cv[5] = a1.y; cv[6] = a1.z; cv[7] = a1.w;
  cv[8] = a2.x; cv[9] = a2.y; cv[10] = a2.z; cv[11] = a2.w;
  cv[12] = a3.x; cv[13] = a3.y; cv[14] = a3.z; cv[15] = a3.w;
  cv[16] = a4.x; cv[17] = a4.y; cv[18] = a4.z; cv[19] = a4.w;
  // y[k] = sum_{i<19} w2[i][k] * u_j[i]   (in-lane; w2 uniform -> scalar lds)
  float y[16];
#pragma unroll
  for (int k = 0; k < 16; ++k) y[k] = 0.f;
#pragma unroll
  for (int i = 0; i < 19; ++i) {
    float ui = cv[i];
#pragma unroll
    for (int k = 0; k < 16; ++k) y[k] += w2[i * 16 + k] * ui;
  }
#pragma unroll
  for (int k = 0; k < 16; ++k) y[k] *= inv;
  wsync();  // Z staging dead; reuse ZB for Y rows
  SLg[sub] = lamc;
#pragma unroll
  for (int t = 0; t < 4; ++t)
    ZB4[sub * 4 + t] =
        make_float4(y[4 * t], y[4 * t + 1], y[4 * t + 2], y[4 * t + 3]);
  wsync();
  // X2[i][sub] = sum_j lamc_j Y[j][i] Y[j][sub]
  if (sub < 16) {
    float acc[16];
#pragma unroll
    for (int i = 0; i < 16; ++i) acc[i] = 0.f;
#pragma unroll
    for (int r = 0; r < 20; ++r) {
      float pr = SLg[r] * ZBf[r * 16 + sub];
#pragma unroll
      for (int t = 0; t < 4; ++t) {
        float4 yr = ZB4[r * 4 + t];  // Y row r, cols 4t..4t+3 (broadcast)
        acc[4 * t + 0] += pr * yr.x;
        acc[4 * t + 1] += pr * yr.y;
        acc[4 * t + 2] += pr * yr.z;
        acc[4 * t + 3] += pr * yr.w;
      }
    }
    float* outb = g_x2 + b * 256;
#pragma unroll
    for (int i = 0; i < 16; ++i) outb[i * 16 + sub] = acc[i];
  }
}

// Stage 2: one-sided Jacobi on 16x16, X3 = Y3^T Lamc Y3 with Y3[j]=w3^T u_j.
// 4 matrices per wave, 64-thread blocks, all lanes active.
__global__ __launch_bounds__(64, 4) void spd_stage2(
    const float* __restrict__ w3) {
  __shared__ float4 Y3L[4 * 16];
  __shared__ float SL2[4 * 16];
  int lane = threadIdx.x;
  int gl = lane >> 4;
  int sub = lane & 15;
  int b = blockIdx.x * 4 + gl;
  float* Y3f = (float*)(Y3L + gl * 16);
  float* SLg = SL2 + gl * 16;

  const float* xb = g_x2 + b * 256;
  float4 b0 = make_float4(xb[0 * 16 + sub], xb[1 * 16 + sub], xb[2 * 16 + sub],
                          xb[3 * 16 + sub]);
  float4 b1 = make_float4(xb[4 * 16 + sub], xb[5 * 16 + sub], xb[6 * 16 + sub],
                          xb[7 * 16 + sub]);
  float4 b2 = make_float4(xb[8 * 16 + sub], xb[9 * 16 + sub],
                          xb[10 * 16 + sub], xb[11 * 16 + sub]);
  float4 b3 = make_float4(xb[12 * 16 + sub], xb[13 * 16 + sub],
                          xb[14 * 16 + sub], xb[15 * 16 + sub]);

  const int bpAddr = (gl * 16 + srcslot(sub, 16)) * 4;
  const bool isP = !(sub & 1);
#pragma unroll 1
  for (int it = 0; it < 60; ++it)  // 4 sweeps
    round16(b0, b1, b2, b3, bpAddr, isP);

  float nOwn = (sq4(b0) + sq4(b1)) + (sq4(b2) + sq4(b3));
  float lamc = fmaxf(sqrtf(nOwn), EPS_REC);
  float nrm = nOwn + 1e-30f;
  float inv = rsqrtf(nrm);
  inv = inv * (1.5f - 0.5f * nrm * inv * inv);
  float cv[16];
  cv[0] = b0.x; cv[1] = b0.y; cv[2] = b0.z; cv[3] = b0.w;
  cv[4] = b1.x; cv[5] = b1.y; cv[6] = b1.z; cv[7] = b1.w;
  cv[8] = b2.x; cv[9] = b2.y; cv[10] = b2.z; cv[11] = b2.w;
  cv[12] = b3.x; cv[13] = b3.y; cv[14] = b3.z; cv[15] = b3.w;
  float y3[4] = {0.f, 0.f, 0.f, 0.f};
#pragma unroll
  for (int i = 0; i < 16; ++i) {
    float ui = cv[i];
#pragma unroll
    for (int j = 0; j < 4; ++j) y3[j] += w3[i * 4 + j] * ui;
  }
#pragma unroll
  for (int j = 0; j < 4; ++j) y3[j] *= inv;
  SLg[sub] = lamc;
  ((float4*)Y3f)[sub] = make_float4(y3[0], y3[1], y3[2], y3[3]);
  wsync();
  int ii = sub >> 2, jj = sub & 3;
  float acc = 0.f;
#pragma unroll
  for (int r = 0; r < 16; ++r)
    acc += SLg[r] * Y3f[r * 4 + ii] * Y3f[r * 4 + jj];
  g_x3[b * 16 + sub] = acc;
}

// Stage 3: per-thread 4x4 LogEig in registers, FC(16->2), log_softmax.
__global__ __launch_bounds__(256) void spd_stage3(const float* __restrict__ fcw,
                                                  float* __restrict__ out) {
  int b = blockIdx.x * 256 + threadIdx.x;
  const float* xb = g_x3 + b * 16;
  float a[4][4];
#pragma unroll
  for (int i = 0; i < 4; ++i)
#pragma unroll
    for (int j = 0; j < 4; ++j) a[i][j] = xb[i * 4 + j];
  float vv[4][4];
#pragma unroll
  for (int i = 0; i < 4; ++i)
#pragma unroll
    for (int j = 0; j < 4; ++j) vv[i][j] = (i == j) ? 1.f : 0.f;

  constexpr int P4[6] = {0, 0, 0, 1, 1, 2};
  constexpr int Q4[6] = {1, 2, 3, 2, 3, 3};
  for (int sw = 0; sw < 6; ++sw) {
#pragma unroll
    for (int e = 0; e < 6; ++e) {
      const int p = P4[e], q = Q4[e];
      float c, s;
      rot_cs(a[p][p], a[q][q], a[p][q], c, s);
#pragma unroll
      for (int j = 0; j < 4; ++j) {
        float xx = a[p][j], yy = a[q][j];
        a[p][j] = c * xx - s * yy;
        a[q][j] = s * xx + c * yy;
      }
#pragma unroll
      for (int i = 0; i < 4; ++i) {
        float xx = a[i][p], yy = a[i][q];
        a[i][p] = c * xx - s * yy;
        a[i][q] = s * xx + c * yy;
      }
#pragma unroll
      for (int i = 0; i < 4; ++i) {
        float xx = vv[i][p], yy = vv[i][q];
        vv[i][p] = c * xx - s * yy;
        vv[i][q] = s * xx + c * yy;
      }
    }
  }
  float ll[4];
#pragma unroll
  for (int r = 0; r < 4; ++r) ll[r] = logf(fmaxf(a[r][r], 1e-12f));
  float feat[16];
#pragma unroll
  for (int i = 0; i < 4; ++i)
#pragma unroll
    for (int j = 0; j < 4; ++j) {
      float acc = 0.f;
#pragma unroll
      for (int r = 0; r < 4; ++r) acc += ll[r] * vv[i][r] * vv[j][r];
      feat[i * 4 + j] = acc;
    }
  float z0 = 0.f, z1 = 0.f;
#pragma unroll
  for (int k = 0; k < 16; ++k) {
    z0 += feat[k] * fcw[2 * k + 0];
    z1 += feat[k] * fcw[2 * k + 1];
  }
  float m = fmaxf(z0, z1);
  float lse = logf(expf(z0 - m) + expf(z1 - m));
  out[b * 2 + 0] = z0 - m - lse;
  out[b * 2 + 1] = z1 - m - lse;
#pragma unroll
  for (int k = 0; k < 16; ++k) out[2 * NB + b * 16 + k] = feat[k];
}

extern "C" void kernel_launch(void* const* d_in, const int* in_sizes, int n_in,
                              void* d_out, int out_size, void* d_ws,
                              size_t ws_size, hipStream_t stream) {
  (void)in_sizes;
  (void)n_in;
  (void)out_size;
  (void)d_ws;
  (void)ws_size;
  const float* x = (const float*)d_in[0];
  const float* w1 = (const float*)d_in[1];
  const float* w2 = (const float*)d_in[2];
  const float* w3 = (const float*)d_in[3];
  const float* fcw = (const float*)d_in[4];
  float* out = (float*)d_out;

  spd_stage1<<<(NB + 2) / 3, 64, 0, stream>>>(x, w1, w2);
  spd_stage2<<<NB / 4, 64, 0, stream>>>(w3);
  spd_stage3<<<NB / 256, 256, 0, stream>>>(fcw, out);
}

// Round 5
// 637.540 us; speedup vs baseline: 1.4037x; 1.0232x over previous
//
#include <hip/hip_runtime.h>
#include <math.h>

#define NB 32768
#define EPS_REC 1e-4f

// Inter-stage staging (static device globals: graph-capture safe).
__device__ float g_x2[NB * 256];  // stage-1 output: B x 16 x 16
__device__ float g_x3[NB * 16];   // stage-2 output: B x 4 x 4

// HISTORY (do not regress):
//  R5: dual-chain ILP (2 matrices/lane-group) -> occupancy halved, +22% time.
//  R6: __launch_bounds__(128,6) -> 85-reg cap -> spills (FETCH 407MB), +60%.
//  R8: 3 sweeps -> absmax 1.375 FAIL. 4 sweeps minimum (plateau 0.25).
//  R9/R10: two-sided, U in regs: 641us. VALU busy-time ~405us.
//  R11: U in LDS: VALU busy UNCHANGED, +10% (b128 LDS ops). Mixed bound.
//  R12: ONE-SIDED Jacobi (col in regs, DPP partner, bpermute tournament):
//       PASSED but FETCH 492/WRITE 961MB scratch, 894us.
//  R13: swp[] deleted: FETCH 441/WRITE 868. VGPR=64 at (64,4)=128 budget.
//  R14: hot state as named float4 SSA vars: FETCH 439/WRITE 852 --
//       BYTE-IDENTICAL to R13 => hot loop was never the scratch source.
//       Unified diagnosis: allocator targets 8 waves/EU (64-VGPR cap,
//       launch_bounds' 2nd arg is only a FLOOR) and deliberately spills the
//       cold preamble/tail arrays (~440B/thread x 700k threads ~= the
//       observed 1.27GB). R12's swp[] additionally pushed the HOT loop over
//       64 -> per-round spills (1.45GB). R6 = same mechanism at 85-reg cap.
//  R15 (this): PIN occupancy: __attribute__((amdgpu_waves_per_eu(4,4)))
//       -> VGPR budget exactly 128 (live peak ~70) -> no incentive to spill.
//       Single change from R14 for clean attribution.
__device__ __forceinline__ void wsync() {
  asm volatile("" ::: "memory");
  __builtin_amdgcn_wave_barrier();
  asm volatile("" ::: "memory");
}

// Swap values between adjacent lanes (lane ^ 1) via DPP quad_perm [1,0,3,2].
// Pairs (2k,2k+1) are even-aligned so they never cross a quad. VALU-pipe op.
__device__ __forceinline__ float dpp_swap1(float x) {
  int xi = __builtin_bit_cast(int, x);
  int yi = __builtin_amdgcn_update_dpp(xi, xi, 0xB1, 0xF, 0xF, true);
  return __builtin_bit_cast(float, yi);
}

// Lane-pull via LDS crossbar (conflict-free permutation). addr = 4*srcLane.
__device__ __forceinline__ float bperm(int addr, float v) {
  int r = __builtin_amdgcn_ds_bpermute(addr, __builtin_bit_cast(int, v));
  return __builtin_bit_cast(float, r);
}

// Tournament (circle-method): content of slot s moves to permf(s); with fixed
// pairing (2k,2k+1), every pair meets exactly once per N-1 rounds.
// srcslot = permf^{-1}: the slot whose content lands in slot `sub`.
__device__ __forceinline__ int srcslot(int sub, int n) {
  return sub == 0 ? 0
       : sub == 1 ? 2
       : sub == n - 2 ? n - 1
       : (sub & 1) ? sub - 2 : sub + 2;
}

// Jacobi rotation (c,s) zeroing the (p,q) off-diagonal of the 2x2 Gram
// [[app,apq],[apq,aqq]]; G = [[c,s],[-s,c]].
__device__ __forceinline__ void rot_cs(float app, float aqq, float apq,
                                       float& c, float& s) {
  float dd = 0.5f * (app - aqq);
  float q2 = apq * apq;
  float hh = dd * dd + q2 + 1e-30f;
  float h = sqrtf(hh);
  float u = fabsf(dd) + h;
  float gi = rsqrtf(u * u + q2);
  c = u * gi;
  float smag = apq * gi;
  s = (dd >= 0.f) ? -smag : smag;
}

// Gram partial: d += <own, partner>, n += <own, own> for 4 components.
__device__ __forceinline__ void gram4(float4 a, float& d0, float& d1,
                                      float& d2, float& d3, float& n0,
                                      float& n1, float& n2, float& n3) {
  float s0 = dpp_swap1(a.x);
  d0 += a.x * s0;
  n0 += a.x * a.x;
  float s1 = dpp_swap1(a.y);
  d1 += a.y * s1;
  n1 += a.y * a.y;
  float s2 = dpp_swap1(a.z);
  d2 += a.z * s2;
  n2 += a.z * a.z;
  float s3 = dpp_swap1(a.w);
  d3 += a.w * s3;
  n3 += a.w * a.w;
}

// Apply rotation + tournament move for 4 components. DPP reads pre-update
// partner values (both pair lanes are at the same program point, and the
// result goes to a fresh value, not back into a before all reads complete).
__device__ __forceinline__ float4 appmv4(float4 a, float c, float beta,
                                         int bpAddr) {
  float4 r;
  r.x = bperm(bpAddr, fmaf(beta, dpp_swap1(a.x), c * a.x));
  r.y = bperm(bpAddr, fmaf(beta, dpp_swap1(a.y), c * a.y));
  r.z = bperm(bpAddr, fmaf(beta, dpp_swap1(a.z), c * a.z));
  r.w = bperm(bpAddr, fmaf(beta, dpp_swap1(a.w), c * a.w));
  return r;
}

// One one-sided Jacobi round on a 20-row column held in a0..a4.
__device__ __forceinline__ void round20(float4& a0, float4& a1, float4& a2,
                                        float4& a3, float4& a4, int bpAddr,
                                        bool isP) {
  float d0 = 0.f, d1 = 0.f, d2 = 0.f, d3 = 0.f;
  float n0 = 0.f, n1 = 0.f, n2 = 0.f, n3 = 0.f;
  gram4(a0, d0, d1, d2, d3, n0, n1, n2, n3);
  gram4(a1, d0, d1, d2, d3, n0, n1, n2, n3);
  gram4(a2, d0, d1, d2, d3, n0, n1, n2, n3);
  gram4(a3, d0, d1, d2, d3, n0, n1, n2, n3);
  gram4(a4, d0, d1, d2, d3, n0, n1, n2, n3);
  float d = (d0 + d1) + (d2 + d3);
  float nOwn = (n0 + n1) + (n2 + n3);
  float nPrt = dpp_swap1(nOwn);
  float ne = isP ? nOwn : nPrt;  // canonical order: both pair lanes identical
  float no = isP ? nPrt : nOwn;
  float c, s;
  rot_cs(ne, no, d, c, s);
  float beta = isP ? -s : s;
  a0 = appmv4(a0, c, beta, bpAddr);
  a1 = appmv4(a1, c, beta, bpAddr);
  a2 = appmv4(a2, c, beta, bpAddr);
  a3 = appmv4(a3, c, beta, bpAddr);
  a4 = appmv4(a4, c, beta, bpAddr);
}

// One one-sided Jacobi round on a 16-row column held in b0..b3.
__device__ __forceinline__ void round16(float4& b0, float4& b1, float4& b2,
                                        float4& b3, int bpAddr, bool isP) {
  float d0 = 0.f, d1 = 0.f, d2 = 0.f, d3 = 0.f;
  float n0 = 0.f, n1 = 0.f, n2 = 0.f, n3 = 0.f;
  gram4(b0, d0, d1, d2, d3, n0, n1, n2, n3);
  gram4(b1, d0, d1, d2, d3, n0, n1, n2, n3);
  gram4(b2, d0, d1, d2, d3, n0, n1, n2, n3);
  gram4(b3, d0, d1, d2, d3, n0, n1, n2, n3);
  float d = (d0 + d1) + (d2 + d3);
  float nOwn = (n0 + n1) + (n2 + n3);
  float nPrt = dpp_swap1(nOwn);
  float ne = isP ? nOwn : nPrt;
  float no = isP ? nPrt : nOwn;
  float c, s;
  rot_cs(ne, no, d, c, s);
  float beta = isP ? -s : s;
  b0 = appmv4(b0, c, beta, bpAddr);
  b1 = appmv4(b1, c, beta, bpAddr);
  b2 = appmv4(b2, c, beta, bpAddr);
  b3 = appmv4(b3, c, beta, bpAddr);
}

__device__ __forceinline__ float sq4(float4 a) {
  return (a.x * a.x + a.y * a.y) + (a.z * a.z + a.w * a.w);
}

// Stage 1: X1 = w1^T X w1 (19 padded to 20), one-sided Jacobi, then
// X2 = Y^T Lamc Y with Y[j] = w2^T u_j. 3 matrices per wave (lanes 60..63
// masked by early return), 64-thread blocks = 1 wave = 3 matrices.
__global__ __launch_bounds__(64)
__attribute__((amdgpu_waves_per_eu(4, 4))) void spd_stage1(
    const float* __restrict__ x, const float* __restrict__ w1,
    const float* __restrict__ w2) {
  __shared__ float4 ZB[3 * 100];  // Z staging, later reused for Y rows
  __shared__ float SL[3 * 20];
  int lane = threadIdx.x;
  int gl = lane / 20;  // 0..3 (3 = idle lanes 60..63)
  int sub = lane - gl * 20;
  int b = blockIdx.x * 3 + gl;
  if (gl >= 3 || b >= NB) return;  // no __syncthreads anywhere: safe
  float4* ZB4 = ZB + gl * 100;
  float* ZBf = (float*)ZB4;
  float* SLg = SL + gl * 20;

  // ---- bilinear: Z = w1^T X (col sub), then X1 col sub = (Z w1) col ----
  const float* xb = x + b * 361;
  float cx[19];
#pragma unroll
  for (int i = 0; i < 19; ++i) cx[i] = (sub < 19) ? xb[i * 19 + sub] : 0.f;
  float z[20];
  z[19] = 0.f;
#pragma unroll
  for (int i = 0; i < 19; ++i) {
    float acc = 0.f;
#pragma unroll
    for (int r = 0; r < 19; ++r) acc += w1[r * 19 + i] * cx[r];
    z[i] = acc;
  }
#pragma unroll
  for (int t = 0; t < 5; ++t)
    ZB4[t * 20 + sub] =
        make_float4(z[4 * t], z[4 * t + 1], z[4 * t + 2], z[4 * t + 3]);
  wsync();
  float wj[19];
#pragma unroll
  for (int r = 0; r < 19; ++r) wj[r] = (sub < 19) ? w1[r * 19 + sub] : 0.f;
  float4 a0 = make_float4(0.f, 0.f, 0.f, 0.f);
  float4 a1 = a0, a2 = a0, a3 = a0, a4 = a0;
#pragma unroll
  for (int r = 0; r < 19; ++r) {
    float wr = wj[r];
    float4 zc;
    zc = ZB4[0 * 20 + r];
    a0.x += zc.x * wr; a0.y += zc.y * wr; a0.z += zc.z * wr; a0.w += zc.w * wr;
    zc = ZB4[1 * 20 + r];
    a1.x += zc.x * wr; a1.y += zc.y * wr; a1.z += zc.z * wr; a1.w += zc.w * wr;
    zc = ZB4[2 * 20 + r];
    a2.x += zc.x * wr; a2.y += zc.y * wr; a2.z += zc.z * wr; a2.w += zc.w * wr;
    zc = ZB4[3 * 20 + r];
    a3.x += zc.x * wr; a3.y += zc.y * wr; a3.z += zc.z * wr; a3.w += zc.w * wr;
    zc = ZB4[4 * 20 + r];
    a4.x += zc.x * wr; a4.y += zc.y * wr; a4.z += zc.z * wr; a4.w += zc.w * wr;
  }
  // a0..a4 = X1 column sub; pad column 19 is exactly 0 (stays 0: d=0 => s=0).

  const int bpAddr = (gl * 20 + srcslot(sub, 20)) * 4;
  const bool isP = !(sub & 1);
#pragma unroll 1
  for (int it = 0; it < 76; ++it)  // 4 sweeps (validated minimum)
    round20(a0, a1, a2, a3, a4, bpAddr, isP);

  // lambda_j = ||col||, u_j = col/||col|| (guarded for the zero pad column)
  float nOwn = ((sq4(a0) + sq4(a1)) + (sq4(a2) + sq4(a3))) + sq4(a4);
  float lamc = fmaxf(sqrtf(nOwn), EPS_REC);
  float nrm = nOwn + 1e-30f;
  float inv = rsqrtf(nrm);
  inv = inv * (1.5f - 0.5f * nrm * inv * inv);  // 1 NR step
  // Unpack to a short-lived static array for the tail.
  float cv[20];
  cv[0] = a0.x; cv[1] = a0.y; cv[2] = a0.z; cv[3] = a0.w;
  cv[4] = a1.x; cv[5] = a1.y; cv[6] = a1.z; cv[7] = a1.w;
  cv[8] = a2.x; cv[9] = a2.y; cv[10] = a2.z; cv[11] = a2.w;
  cv[12] = a3.x; cv[13] = a3.y; cv[14] = a3.z; cv[15] = a3.w;
  cv[16] = a4.x; cv[17] = a4.y; cv[18] = a4.z; cv[19] = a4.w;
  // y[k] = sum_{i<19} w2[i][k] * u_j[i]   (in-lane; w2 uniform -> scalar lds)
  float y[16];
#pragma unroll
  for (int k = 0; k < 16; ++k) y[k] = 0.f;
#pragma unroll
  for (int i = 0; i < 19; ++i) {
    float ui = cv[i];
#pragma unroll
    for (int k = 0; k < 16; ++k) y[k] += w2[i * 16 + k] * ui;
  }
#pragma unroll
  for (int k = 0; k < 16; ++k) y[k] *= inv;
  wsync();  // Z staging dead; reuse ZB for Y rows
  SLg[sub] = lamc;
#pragma unroll
  for (int t = 0; t < 4; ++t)
    ZB4[sub * 4 + t] =
        make_float4(y[4 * t], y[4 * t + 1], y[4 * t + 2], y[4 * t + 3]);
  wsync();
  // X2[i][sub] = sum_j lamc_j Y[j][i] Y[j][sub]
  if (sub < 16) {
    float acc[16];
#pragma unroll
    for (int i = 0; i < 16; ++i) acc[i] = 0.f;
#pragma unroll
    for (int r = 0; r < 20; ++r) {
      float pr = SLg[r] * ZBf[r * 16 + sub];
#pragma unroll
      for (int t = 0; t < 4; ++t) {
        float4 yr = ZB4[r * 4 + t];  // Y row r, cols 4t..4t+3 (broadcast)
        acc[4 * t + 0] += pr * yr.x;
        acc[4 * t + 1] += pr * yr.y;
        acc[4 * t + 2] += pr * yr.z;
        acc[4 * t + 3] += pr * yr.w;
      }
    }
    float* outb = g_x2 + b * 256;
#pragma unroll
    for (int i = 0; i < 16; ++i) outb[i * 16 + sub] = acc[i];
  }
}

// Stage 2: one-sided Jacobi on 16x16, X3 = Y3^T Lamc Y3 with Y3[j]=w3^T u_j.
// 4 matrices per wave, 64-thread blocks, all lanes active.
__global__ __launch_bounds__(64)
__attribute__((amdgpu_waves_per_eu(4, 4))) void spd_stage2(
    const float* __restrict__ w3) {
  __shared__ float4 Y3L[4 * 16];
  __shared__ float SL2[4 * 16];
  int lane = threadIdx.x;
  int gl = lane >> 4;
  int sub = lane & 15;
  int b = blockIdx.x * 4 + gl;
  float* Y3f = (float*)(Y3L + gl * 16);
  float* SLg = SL2 + gl * 16;

  const float* xb = g_x2 + b * 256;
  float4 b0 = make_float4(xb[0 * 16 + sub], xb[1 * 16 + sub], xb[2 * 16 + sub],
                          xb[3 * 16 + sub]);
  float4 b1 = make_float4(xb[4 * 16 + sub], xb[5 * 16 + sub], xb[6 * 16 + sub],
                          xb[7 * 16 + sub]);
  float4 b2 = make_float4(xb[8 * 16 + sub], xb[9 * 16 + sub],
                          xb[10 * 16 + sub], xb[11 * 16 + sub]);
  float4 b3 = make_float4(xb[12 * 16 + sub], xb[13 * 16 + sub],
                          xb[14 * 16 + sub], xb[15 * 16 + sub]);

  const int bpAddr = (gl * 16 + srcslot(sub, 16)) * 4;
  const bool isP = !(sub & 1);
#pragma unroll 1
  for (int it = 0; it < 60; ++it)  // 4 sweeps
    round16(b0, b1, b2, b3, bpAddr, isP);

  float nOwn = (sq4(b0) + sq4(b1)) + (sq4(b2) + sq4(b3));
  float lamc = fmaxf(sqrtf(nOwn), EPS_REC);
  float nrm = nOwn + 1e-30f;
  float inv = rsqrtf(nrm);
  inv = inv * (1.5f - 0.5f * nrm * inv * inv);
  float cv[16];
  cv[0] = b0.x; cv[1] = b0.y; cv[2] = b0.z; cv[3] = b0.w;
  cv[4] = b1.x; cv[5] = b1.y; cv[6] = b1.z; cv[7] = b1.w;
  cv[8] = b2.x; cv[9] = b2.y; cv[10] = b2.z; cv[11] = b2.w;
  cv[12] = b3.x; cv[13] = b3.y; cv[14] = b3.z; cv[15] = b3.w;
  float y3[4] = {0.f, 0.f, 0.f, 0.f};
#pragma unroll
  for (int i = 0; i < 16; ++i) {
    float ui = cv[i];
#pragma unroll
    for (int j = 0; j < 4; ++j) y3[j] += w3[i * 4 + j] * ui;
  }
#pragma unroll
  for (int j = 0; j < 4; ++j) y3[j] *= inv;
  SLg[sub] = lamc;
  ((float4*)Y3f)[sub] = make_float4(y3[0], y3[1], y3[2], y3[3]);
  wsync();
  int ii = sub >> 2, jj = sub & 3;
  float acc = 0.f;
#pragma unroll
  for (int r = 0; r < 16; ++r)
    acc += SLg[r] * Y3f[r * 4 + ii] * Y3f[r * 4 + jj];
  g_x3[b * 16 + sub] = acc;
}

// Stage 3: per-thread 4x4 LogEig in registers, FC(16->2), log_softmax.
__global__ __launch_bounds__(256) void spd_stage3(const float* __restrict__ fcw,
                                                  float* __restrict__ out) {
  int b = blockIdx.x * 256 + threadIdx.x;
  const float* xb = g_x3 + b * 16;
  float a[4][4];
#pragma unroll
  for (int i = 0; i < 4; ++i)
#pragma unroll
    for (int j = 0; j < 4; ++j) a[i][j] = xb[i * 4 + j];
  float vv[4][4];
#pragma unroll
  for (int i = 0; i < 4; ++i)
#pragma unroll
    for (int j = 0; j < 4; ++j) vv[i][j] = (i == j) ? 1.f : 0.f;

  constexpr int P4[6] = {0, 0, 0, 1, 1, 2};
  constexpr int Q4[6] = {1, 2, 3, 2, 3, 3};
  for (int sw = 0; sw < 6; ++sw) {
#pragma unroll
    for (int e = 0; e < 6; ++e) {
      const int p = P4[e], q = Q4[e];
      float c, s;
      rot_cs(a[p][p], a[q][q], a[p][q], c, s);
#pragma unroll
      for (int j = 0; j < 4; ++j) {
        float xx = a[p][j], yy = a[q][j];
        a[p][j] = c * xx - s * yy;
        a[q][j] = s * xx + c * yy;
      }
#pragma unroll
      for (int i = 0; i < 4; ++i) {
        float xx = a[i][p], yy = a[i][q];
        a[i][p] = c * xx - s * yy;
        a[i][q] = s * xx + c * yy;
      }
#pragma unroll
      for (int i = 0; i < 4; ++i) {
        float xx = vv[i][p], yy = vv[i][q];
        vv[i][p] = c * xx - s * yy;
        vv[i][q] = s * xx + c * yy;
      }
    }
  }
  float ll[4];
#pragma unroll
  for (int r = 0; r < 4; ++r) ll[r] = logf(fmaxf(a[r][r], 1e-12f));
  float feat[16];
#pragma unroll
  for (int i = 0; i < 4; ++i)
#pragma unroll
    for (int j = 0; j < 4; ++j) {
      float acc = 0.f;
#pragma unroll
      for (int r = 0; r < 4; ++r) acc += ll[r] * vv[i][r] * vv[j][r];
      feat[i * 4 + j] = acc;
    }
  float z0 = 0.f, z1 = 0.f;
#pragma unroll
  for (int k = 0; k < 16; ++k) {
    z0 += feat[k] * fcw[2 * k + 0];
    z1 += feat[k] * fcw[2 * k + 1];
  }
  float m = fmaxf(z0, z1);
  float lse = logf(expf(z0 - m) + expf(z1 - m));
  out[b * 2 + 0] = z0 - m - lse;
  out[b * 2 + 1] = z1 - m - lse;
#pragma unroll
  for (int k = 0; k < 16; ++k) out[2 * NB + b * 16 + k] = feat[k];
}

extern "C" void kernel_launch(void* const* d_in, const int* in_sizes, int n_in,
                              void* d_out, int out_size, void* d_ws,
                              size_t ws_size, hipStream_t stream) {
  (void)in_sizes;
  (void)n_in;
  (void)out_size;
  (void)d_ws;
  (void)ws_size;
  const float* x = (const float*)d_in[0];
  const float* w1 = (const float*)d_in[1];
  const float* w2 = (const float*)d_in[2];
  const float* w3 = (const float*)d_in[3];
  const float* fcw = (const float*)d_in[4];
  float* out = (float*)d_out;

  spd_stage1<<<(NB + 2) / 3, 64, 0, stream>>>(x, w1, w2);
  spd_stage2<<<NB / 4, 64, 0, stream>>>(w3);
  spd_stage3<<<NB / 256, 256, 0, stream>>>(fcw, out);
}